// Round 9
// baseline (421.347 us; speedup 1.0000x reference)
//
#include <hip/hip_runtime.h>
#include <hip/hip_cooperative_groups.h>
#include <math.h>

namespace cg = cooperative_groups;

#define N_NODES 50000
#define N_EDGES 800000
#define EP (N_EDGES + N_NODES)   // 850000 edges incl. self loops
#define NEG 0.2f
#define SCAN_BLOCKS 49           // ceil(50000/1024)
#define BLD_BLOCKS 256
#define BLD_THREADS 65536
// xp1b row: 256 bf16 channels (512B) + 8 fp32 as1 (32B) + 96B pad = 640B
#define ROW_US 320               // ushorts per row

typedef __attribute__((ext_vector_type(8))) short bf16x8;
typedef __attribute__((ext_vector_type(4))) float f32x4;
typedef __attribute__((ext_vector_type(2))) float f32x2;

static __device__ __forceinline__ unsigned short bf16_rn(float f) {
    union { float f; unsigned int u; } v; v.f = f;
    unsigned int u = v.u;
    unsigned int r = (u + 0x7FFFu + ((u >> 16) & 1u)) >> 16;
    return (unsigned short)r;
}
static __device__ __forceinline__ f32x2 bf2_unpack(unsigned int u) {
    union { unsigned int i; float f; } a, b;
    a.i = u << 16; b.i = u & 0xFFFF0000u;
    return (f32x2){a.f, b.f};
}

// ---------------- fused CSR build + W-frag convert (cooperative) ----------------
// P0 zero counts/fill + cvtW | P1 hist | P2 chunk scans | P3 offset add | P4 scatter
__global__ void k_build(const int* __restrict__ ei, int* __restrict__ counts,
                        int* __restrict__ fill, int* __restrict__ row_ptr,
                        int* __restrict__ bsums, int* __restrict__ colb,
                        const float* __restrict__ W1, bf16x8* __restrict__ Wfrag) {
    cg::grid_group grid = cg::this_grid();
    __shared__ int wsum[4];
    __shared__ int soff;
    int t = threadIdx.x, b = blockIdx.x;
    int tid = b * 256 + t;

    // P0: zero counts+fill (contiguous) and convert W1 -> pi-permuted B frags
    for (int i = tid; i < 2 * N_NODES; i += BLD_THREADS) counts[i] = 0;
    if (tid < 8192) {
        int ft = tid;
        int c = ft >> 10, rem = ft & 1023;
        int nt = rem >> 6, l = rem & 63;
        int n = (l & 15) * 16 + nt;
        int k0 = c * 32 + (l >> 4) * 8;
        bf16x8 f;
        #pragma unroll
        for (int j = 0; j < 8; ++j)
            f[j] = (short)bf16_rn(W1[(k0 + j) * 256 + n]);
        Wfrag[ft] = f;
    }
    grid.sync();

    // P1: histogram of destinations
    for (int e = tid; e < EP; e += BLD_THREADS) {
        int d = (e < N_EDGES) ? ei[N_EDGES + e] : (e - N_EDGES);
        atomicAdd(&counts[d], 1);
    }
    grid.sync();

    // P2: per-chunk exclusive scan (blocks 0..48, 1024 elems each)
    if (b < SCAN_BLOCKS) {
        int lane = t & 63, w = t >> 6;
        int i0 = b * 1024 + t * 4;
        int v0 = (i0 + 0 < N_NODES) ? counts[i0 + 0] : 0;
        int v1 = (i0 + 1 < N_NODES) ? counts[i0 + 1] : 0;
        int v2 = (i0 + 2 < N_NODES) ? counts[i0 + 2] : 0;
        int v3 = (i0 + 3 < N_NODES) ? counts[i0 + 3] : 0;
        int s = v0 + v1 + v2 + v3;
        int incl = s;
        #pragma unroll
        for (int d = 1; d < 64; d <<= 1) {
            int u = __shfl_up(incl, d);
            if (lane >= d) incl += u;
        }
        if (lane == 63) wsum[w] = incl;
        __syncthreads();
        if (t == 0) {
            int run = 0;
            #pragma unroll
            for (int i = 0; i < 4; ++i) { int x = wsum[i]; wsum[i] = run; run += x; }
            bsums[b] = run;
        }
        __syncthreads();
        int base = wsum[w] + incl - s;
        if (i0 + 0 < N_NODES) row_ptr[i0 + 0] = base;
        if (i0 + 1 < N_NODES) row_ptr[i0 + 1] = base + v0;
        if (i0 + 2 < N_NODES) row_ptr[i0 + 2] = base + v0 + v1;
        if (i0 + 3 < N_NODES) row_ptr[i0 + 3] = base + v0 + v1 + v2;
    }
    grid.sync();

    // P3: add scanned block offsets
    if (b < SCAN_BLOCKS) {
        if (t < 64) {
            int v = (t < SCAN_BLOCKS) ? bsums[t] : 0;
            int incl = v;
            #pragma unroll
            for (int d = 1; d < 64; d <<= 1) {
                int u = __shfl_up(incl, d);
                if (t >= d) incl += u;
            }
            if (t == b) soff = incl - v;
        }
        __syncthreads();
        int off = soff;
        int i0 = b * 1024 + t * 4;
        #pragma unroll
        for (int j = 0; j < 4; ++j)
            if (i0 + j < N_NODES) row_ptr[i0 + j] += off;
        if (b == 0 && t == 0) row_ptr[N_NODES] = EP;
    }
    grid.sync();

    // P4: scatter sources into CSR
    for (int e = tid; e < EP; e += BLD_THREADS) {
        int s, d;
        if (e < N_EDGES) { s = ei[e]; d = ei[N_EDGES + e]; }
        else             { s = e - N_EDGES; d = s; }
        int pos = row_ptr[d] + atomicAdd(&fill[d], 1);
        colb[pos] = s;
    }
}

// ---------------- Layer 1 GEMM via bf16 MFMA + fused attention logits ----------------
// xp1b rows (640B): [0..511] bf16 channels, [512..543] as1[8] fp32, pad.
#define GM_GRID 782   // ceil(50000/64)
__global__ __launch_bounds__(128) void
k_gemm1m(const float* __restrict__ x, const bf16x8* __restrict__ Wfrag,
         unsigned short* __restrict__ xp1b,
         const float* __restrict__ asrc, const float* __restrict__ adst,
         float* __restrict__ ad1) {
    __shared__ bf16x8 lds[1024];   // one K=32 chunk of B frags: 16 KB
    int t = threadIdx.x, l = t & 63, w = t >> 6;
    int rowbase = blockIdx.x * 64 + w * 32;
    int m = l & 15, kg = l >> 4;

    f32x4 acc0[16], acc1[16];
    #pragma unroll
    for (int nt = 0; nt < 16; ++nt) {
        acc0[nt] = (f32x4){0.f, 0.f, 0.f, 0.f};
        acc1[nt] = (f32x4){0.f, 0.f, 0.f, 0.f};
    }

    int r0 = rowbase + m;
    int r1 = rowbase + 16 + m;
    if (r0 > N_NODES - 1) r0 = N_NODES - 1;   // clamp (results unused)
    if (r1 > N_NODES - 1) r1 = N_NODES - 1;
    const float4* x4 = (const float4*)x;

    for (int c = 0; c < 8; ++c) {
        __syncthreads();
        const bf16x8* src = Wfrag + c * 1024;
        #pragma unroll
        for (int q = 0; q < 8; ++q)
            lds[q * 128 + t] = src[q * 128 + t];
        __syncthreads();

        int kb = (c * 32 + kg * 8) >> 2;
        float4 xa0 = x4[r0 * 64 + kb], xb0 = x4[r0 * 64 + kb + 1];
        float4 xa1 = x4[r1 * 64 + kb], xb1 = x4[r1 * 64 + kb + 1];
        bf16x8 aF0, aF1;
        aF0[0] = (short)bf16_rn(xa0.x); aF0[1] = (short)bf16_rn(xa0.y);
        aF0[2] = (short)bf16_rn(xa0.z); aF0[3] = (short)bf16_rn(xa0.w);
        aF0[4] = (short)bf16_rn(xb0.x); aF0[5] = (short)bf16_rn(xb0.y);
        aF0[6] = (short)bf16_rn(xb0.z); aF0[7] = (short)bf16_rn(xb0.w);
        aF1[0] = (short)bf16_rn(xa1.x); aF1[1] = (short)bf16_rn(xa1.y);
        aF1[2] = (short)bf16_rn(xa1.z); aF1[3] = (short)bf16_rn(xa1.w);
        aF1[4] = (short)bf16_rn(xb1.x); aF1[5] = (short)bf16_rn(xb1.y);
        aF1[6] = (short)bf16_rn(xb1.z); aF1[7] = (short)bf16_rn(xb1.w);

        #pragma unroll
        for (int nt = 0; nt < 16; ++nt) {
            bf16x8 bF = lds[nt * 64 + l];
            acc0[nt] = __builtin_amdgcn_mfma_f32_16x16x32_bf16(aF0, bF, acc0[nt], 0, 0, 0);
            acc1[nt] = __builtin_amdgcn_mfma_f32_16x16x32_bf16(aF1, bF, acc1[nt], 0, 0, 0);
        }
    }

    // epilogue: lane holds channels cbase*16+nt of rows rq*4+reg (pi-permuted)
    int cbase = l & 15, rq = l >> 4;
    float asV[16], adV[16];
    #pragma unroll
    for (int q = 0; q < 4; ++q) {
        float4 sa = ((const float4*)asrc)[cbase * 4 + q];
        float4 da = ((const float4*)adst)[cbase * 4 + q];
        asV[q * 4 + 0] = sa.x; asV[q * 4 + 1] = sa.y; asV[q * 4 + 2] = sa.z; asV[q * 4 + 3] = sa.w;
        adV[q * 4 + 0] = da.x; adV[q * 4 + 1] = da.y; adV[q * 4 + 2] = da.z; adV[q * 4 + 3] = da.w;
    }
    #pragma unroll
    for (int g = 0; g < 2; ++g) {
        f32x4* A = g ? acc1 : acc0;
        #pragma unroll
        for (int reg = 0; reg < 4; ++reg) {
            int gr = rowbase + g * 16 + rq * 4 + reg;
            unsigned int ob[8];
            float ps = 0.f, pd = 0.f;
            #pragma unroll
            for (int q = 0; q < 8; ++q) {
                float v0 = A[2 * q][reg], v1 = A[2 * q + 1][reg];
                ob[q] = (unsigned int)bf16_rn(v0) | ((unsigned int)bf16_rn(v1) << 16);
                ps = fmaf(v0, asV[2 * q], ps);     ps = fmaf(v1, asV[2 * q + 1], ps);
                pd = fmaf(v0, adV[2 * q], pd);     pd = fmaf(v1, adV[2 * q + 1], pd);
            }
            ps += __shfl_xor(ps, 1);
            pd += __shfl_xor(pd, 1);
            if (gr < N_NODES) {
                unsigned short* row = xp1b + (size_t)gr * ROW_US;
                uint4* dst = (uint4*)(row + cbase * 16);
                dst[0] = make_uint4(ob[0], ob[1], ob[2], ob[3]);
                dst[1] = make_uint4(ob[4], ob[5], ob[6], ob[7]);
                if ((l & 1) == 0) {
                    ((float*)(row + 256))[cbase >> 1] = ps;   // as1 in-row
                    ad1[gr * 8 + (cbase >> 1)] = pd;
                }
            }
        }
    }
}

// ---------------- fused layer-1 softmax-aggregate + ReLU + layer-2 proj/logits ----
// Gather indices scalarized via readfirstlane -> SGPR row base + lane offset;
// as1 co-located in the row (one base serves both loads).
__global__ void k_agg1(const unsigned short* __restrict__ xp1b, const float* __restrict__ ad1,
                       const int* __restrict__ row_ptr, const int* __restrict__ colb,
                       const float* __restrict__ b1, const float* __restrict__ W2,
                       const float* __restrict__ as2w, const float* __restrict__ ad2w,
                       float* __restrict__ xp2, float* __restrict__ as2,
                       float* __restrict__ ad2) {
    int t = threadIdx.x, l = t & 63, w = t >> 6;
    int n = blockIdx.x * 4 + w;
    int hidx = l >> 3;
    float adn = ad1[n * 8 + hidx];
    int start = row_ptr[n], end = row_ptr[n + 1];
    const char* xb = (const char*)xp1b;
    int loff = 8 * l;
    int aoff = 512 + 4 * hidx;
    f32x2 accA = {0.f, 0.f}, accB = {0.f, 0.f};
    float den = 0.f;
    int j = start;
    for (; j + 8 <= end; j += 8) {
        int s0 = __builtin_amdgcn_readfirstlane(colb[j]);
        int s1 = __builtin_amdgcn_readfirstlane(colb[j + 1]);
        int s2 = __builtin_amdgcn_readfirstlane(colb[j + 2]);
        int s3 = __builtin_amdgcn_readfirstlane(colb[j + 3]);
        int s4 = __builtin_amdgcn_readfirstlane(colb[j + 4]);
        int s5 = __builtin_amdgcn_readfirstlane(colb[j + 5]);
        int s6 = __builtin_amdgcn_readfirstlane(colb[j + 6]);
        int s7 = __builtin_amdgcn_readfirstlane(colb[j + 7]);
        const char* p0 = xb + (size_t)s0 * 640;
        const char* p1 = xb + (size_t)s1 * 640;
        const char* p2 = xb + (size_t)s2 * 640;
        const char* p3 = xb + (size_t)s3 * 640;
        const char* p4 = xb + (size_t)s4 * 640;
        const char* p5 = xb + (size_t)s5 * 640;
        const char* p6 = xb + (size_t)s6 * 640;
        const char* p7 = xb + (size_t)s7 * 640;
        uint2 r0 = *(const uint2*)(p0 + loff);
        uint2 r1 = *(const uint2*)(p1 + loff);
        uint2 r2 = *(const uint2*)(p2 + loff);
        uint2 r3 = *(const uint2*)(p3 + loff);
        uint2 r4 = *(const uint2*)(p4 + loff);
        uint2 r5 = *(const uint2*)(p5 + loff);
        uint2 r6 = *(const uint2*)(p6 + loff);
        uint2 r7 = *(const uint2*)(p7 + loff);
        float e0 = *(const float*)(p0 + aoff) + adn;
        float e1 = *(const float*)(p1 + aoff) + adn;
        float e2 = *(const float*)(p2 + aoff) + adn;
        float e3 = *(const float*)(p3 + aoff) + adn;
        float e4 = *(const float*)(p4 + aoff) + adn;
        float e5 = *(const float*)(p5 + aoff) + adn;
        float e6 = *(const float*)(p6 + aoff) + adn;
        float e7 = *(const float*)(p7 + aoff) + adn;
        e0 = (e0 > 0.f) ? e0 : NEG * e0;
        e1 = (e1 > 0.f) ? e1 : NEG * e1;
        e2 = (e2 > 0.f) ? e2 : NEG * e2;
        e3 = (e3 > 0.f) ? e3 : NEG * e3;
        e4 = (e4 > 0.f) ? e4 : NEG * e4;
        e5 = (e5 > 0.f) ? e5 : NEG * e5;
        e6 = (e6 > 0.f) ? e6 : NEG * e6;
        e7 = (e7 > 0.f) ? e7 : NEG * e7;
        float p0e = __expf(e0), p1e = __expf(e1), p2e = __expf(e2), p3e = __expf(e3);
        float p4e = __expf(e4), p5e = __expf(e5), p6e = __expf(e6), p7e = __expf(e7);
        den += ((p0e + p1e) + (p2e + p3e)) + ((p4e + p5e) + (p6e + p7e));
        f32x2 q;
        q = (f32x2){p0e, p0e}; accA += q * bf2_unpack(r0.x); accB += q * bf2_unpack(r0.y);
        q = (f32x2){p1e, p1e}; accA += q * bf2_unpack(r1.x); accB += q * bf2_unpack(r1.y);
        q = (f32x2){p2e, p2e}; accA += q * bf2_unpack(r2.x); accB += q * bf2_unpack(r2.y);
        q = (f32x2){p3e, p3e}; accA += q * bf2_unpack(r3.x); accB += q * bf2_unpack(r3.y);
        q = (f32x2){p4e, p4e}; accA += q * bf2_unpack(r4.x); accB += q * bf2_unpack(r4.y);
        q = (f32x2){p5e, p5e}; accA += q * bf2_unpack(r5.x); accB += q * bf2_unpack(r5.y);
        q = (f32x2){p6e, p6e}; accA += q * bf2_unpack(r6.x); accB += q * bf2_unpack(r6.y);
        q = (f32x2){p7e, p7e}; accA += q * bf2_unpack(r7.x); accB += q * bf2_unpack(r7.y);
    }
    for (; j < end; ++j) {
        int s = __builtin_amdgcn_readfirstlane(colb[j]);
        const char* p = xb + (size_t)s * 640;
        uint2 r = *(const uint2*)(p + loff);
        float e = *(const float*)(p + aoff) + adn;
        e = (e > 0.f) ? e : NEG * e;
        float pe = __expf(e);
        den += pe;
        f32x2 q = {pe, pe};
        accA += q * bf2_unpack(r.x);
        accB += q * bf2_unpack(r.y);
    }
    float4 bv = ((const float4*)b1)[l];
    float inv = 1.f / den;
    float4 o;
    o.x = fmaxf(accA[0] * inv + bv.x, 0.f);
    o.y = fmaxf(accA[1] * inv + bv.y, 0.f);
    o.z = fmaxf(accB[0] * inv + bv.z, 0.f);
    o.w = fmaxf(accB[1] * inv + bv.w, 0.f);
    // fused proj2: W2 row-major (256,2); lane l holds channels 4l..4l+3
    float4 wa = ((const float4*)W2)[2 * l];
    float4 wb = ((const float4*)W2)[2 * l + 1];
    float d0 = o.x * wa.x + o.y * wa.z + o.z * wb.x + o.w * wb.z;
    float d1 = o.x * wa.y + o.y * wa.w + o.z * wb.y + o.w * wb.w;
    #pragma unroll
    for (int m = 1; m < 64; m <<= 1) {
        d0 += __shfl_xor(d0, m);
        d1 += __shfl_xor(d1, m);
    }
    if (l == 0) {
        xp2[2 * n] = d0;
        xp2[2 * n + 1] = d1;
        as2[n] = d0 * as2w[0] + d1 * as2w[1];
        ad2[n] = d0 * ad2w[0] + d1 * ad2w[1];
    }
}

// ---------------- segment-softmax + aggregate, layer 2: node-per-lane ----------------
__global__ void k_agg2(const float* __restrict__ xp2, const float* __restrict__ as2,
                       const float* __restrict__ ad2, const int* __restrict__ row_ptr,
                       const int* __restrict__ colb, const float* __restrict__ b2,
                       float* __restrict__ out) {
    int n = blockIdx.x * 256 + threadIdx.x;
    if (n >= N_NODES) return;
    int start = row_ptr[n], end = row_ptr[n + 1];
    float adn = ad2[n];
    float b20 = b2[0], b21 = b2[1];
    float a0 = 0.f, a1 = 0.f, den = 0.f;
    const float2* xpv = (const float2*)xp2;
    for (int j = start; j < end; ++j) {
        int s = colb[j];
        float e = as2[s] + adn;
        e = (e > 0.f) ? e : NEG * e;
        float p = __expf(e);
        den += p;
        float2 v = xpv[s];
        a0 = fmaf(p, v.x, a0);
        a1 = fmaf(p, v.y, a1);
    }
    float inv = 1.f / den;
    ((float2*)out)[n] = make_float2(a0 * inv + b20, a1 * inv + b21);
}

extern "C" void kernel_launch(void* const* d_in, const int* in_sizes, int n_in,
                              void* d_out, int out_size, void* d_ws, size_t ws_size,
                              hipStream_t stream) {
    const float* x     = (const float*)d_in[0];
    const int*   ei    = (const int*)d_in[1];
    const float* W1    = (const float*)d_in[2];
    const float* asrc1 = (const float*)d_in[3];
    const float* adst1 = (const float*)d_in[4];
    const float* b1    = (const float*)d_in[5];
    const float* W2    = (const float*)d_in[6];
    const float* asrc2 = (const float*)d_in[7];
    const float* adst2 = (const float*)d_in[8];
    const float* b2    = (const float*)d_in[9];
    float* out = (float*)d_out;

    char* ws = (char*)d_ws;
    unsigned short* xp1b = (unsigned short*)(ws + 0);   // 32,000,000 B (640B rows)
    bf16x8* Wfrag  = (bf16x8*)(ws + 32000000);      //    131,072 B
    float* ad1     = (float*)(ws + 32200000);       //  1,600,000 B
    float* xp2     = (float*)(ws + 33800000);       //    400,000 B
    float* as2     = (float*)(ws + 34200000);       //    200,000 B
    float* ad2     = (float*)(ws + 34400000);       //    200,000 B
    int*   counts  = (int*)  (ws + 34600000);       //    200,000 B
    int*   fill    = (int*)  (ws + 34800000);       //    200,000 B (= counts+N)
    int*   row_ptr = (int*)  (ws + 35000000);       //    200,064 B
    int*   colb    = (int*)  (ws + 35200064);       //  3,400,000 B
    int*   bsums   = (int*)  (ws + 38600064);       //        256 B

    void* bargs[] = {(void*)&ei, (void*)&counts, (void*)&fill, (void*)&row_ptr,
                     (void*)&bsums, (void*)&colb, (void*)&W1, (void*)&Wfrag};
    hipLaunchCooperativeKernel((void*)k_build, dim3(BLD_BLOCKS), dim3(256),
                               bargs, 0, stream);

    k_gemm1m <<<GM_GRID, 128, 0, stream>>>(x, Wfrag, xp1b, asrc1, adst1, ad1);
    k_agg1   <<<12500,  256, 0, stream>>>(xp1b, ad1, row_ptr, colb,
                                          b1, W2, asrc2, adst2, xp2, as2, ad2);
    k_agg2   <<<196,    256, 0, stream>>>(xp2, as2, ad2, row_ptr, colb, b2, out);
}

// Round 10
// 299.626 us; speedup vs baseline: 1.4062x; 1.4062x over previous
//
#include <hip/hip_runtime.h>
#include <math.h>

#define N_NODES 50000
#define N_EDGES 800000
#define EP (N_EDGES + N_NODES)   // 850000 edges incl. self loops
#define NEG 0.2f
#define SCAN_BLOCKS 49           // ceil(50000/1024)
// xp1b row: 256 bf16 channels (512B) + 8 fp32 as1 (32B) + 96B pad = 640B
#define ROW_US 320               // ushorts per row

typedef __attribute__((ext_vector_type(8))) short bf16x8;
typedef __attribute__((ext_vector_type(4))) float f32x4;
typedef __attribute__((ext_vector_type(2))) float f32x2;

static __device__ __forceinline__ unsigned short bf16_rn(float f) {
    union { float f; unsigned int u; } v; v.f = f;
    unsigned int u = v.u;
    unsigned int r = (u + 0x7FFFu + ((u >> 16) & 1u)) >> 16;
    return (unsigned short)r;
}
static __device__ __forceinline__ f32x2 bf2_unpack(unsigned int u) {
    union { unsigned int i; float f; } a, b;
    a.i = u << 16; b.i = u & 0xFFFF0000u;
    return (f32x2){a.f, b.f};
}

// ---------------- CSR build (separate dispatches; R9's cooperative fusion
// regressed 130us: cooperative launch caps at 1 block/CU = 11% occupancy) ----

__global__ void k_hist(const int* __restrict__ ei, int* __restrict__ counts) {
    int e = blockIdx.x * 256 + threadIdx.x;
    if (e >= EP) return;
    int d = (e < N_EDGES) ? ei[N_EDGES + e] : (e - N_EDGES);
    atomicAdd(&counts[d], 1);
}

__global__ void k_scan_block(const int* __restrict__ counts, int* __restrict__ excl,
                             int* __restrict__ bsums) {
    __shared__ int wsum[4];
    int b = blockIdx.x, t = threadIdx.x;
    int lane = t & 63, w = t >> 6;
    int i0 = b * 1024 + t * 4;
    int v0 = (i0 + 0 < N_NODES) ? counts[i0 + 0] : 0;
    int v1 = (i0 + 1 < N_NODES) ? counts[i0 + 1] : 0;
    int v2 = (i0 + 2 < N_NODES) ? counts[i0 + 2] : 0;
    int v3 = (i0 + 3 < N_NODES) ? counts[i0 + 3] : 0;
    int s = v0 + v1 + v2 + v3;
    int incl = s;
    #pragma unroll
    for (int d = 1; d < 64; d <<= 1) {
        int u = __shfl_up(incl, d);
        if (lane >= d) incl += u;
    }
    if (lane == 63) wsum[w] = incl;
    __syncthreads();
    if (t == 0) {
        int run = 0;
        #pragma unroll
        for (int i = 0; i < 4; ++i) { int x = wsum[i]; wsum[i] = run; run += x; }
        bsums[b] = run;   // block total
    }
    __syncthreads();
    int base = wsum[w] + incl - s;
    if (i0 + 0 < N_NODES) excl[i0 + 0] = base;
    if (i0 + 1 < N_NODES) excl[i0 + 1] = base + v0;
    if (i0 + 2 < N_NODES) excl[i0 + 2] = base + v0 + v1;
    if (i0 + 3 < N_NODES) excl[i0 + 3] = base + v0 + v1 + v2;
}

// scan_mid folded in: every block wave-scans the 49 block sums itself
__global__ void k_scan_add(int* __restrict__ row_ptr, const int* __restrict__ bsums) {
    __shared__ int soff;
    int b = blockIdx.x, t = threadIdx.x;
    if (t < 64) {
        int v = (t < SCAN_BLOCKS) ? bsums[t] : 0;
        int incl = v;
        #pragma unroll
        for (int d = 1; d < 64; d <<= 1) {
            int u = __shfl_up(incl, d);
            if (t >= d) incl += u;
        }
        if (t == b) soff = incl - v;
    }
    __syncthreads();
    int off = soff;
    int i0 = b * 1024 + t * 4;
    #pragma unroll
    for (int j = 0; j < 4; ++j)
        if (i0 + j < N_NODES) row_ptr[i0 + j] += off;
    if (b == 0 && t == 0) row_ptr[N_NODES] = EP;
}

__global__ void k_scatter(const int* __restrict__ ei, const int* __restrict__ row_ptr,
                          int* __restrict__ fill, int* __restrict__ colb) {
    int e = blockIdx.x * 256 + threadIdx.x;
    if (e >= EP) return;
    int s, d;
    if (e < N_EDGES) { s = ei[e]; d = ei[N_EDGES + e]; }
    else             { s = e - N_EDGES; d = s; }
    int pos = row_ptr[d] + atomicAdd(&fill[d], 1);
    colb[pos] = s;
}

// ---------------- W1 -> MFMA B-fragment order (pi-permuted), bf16 ----------------
__global__ void k_cvtWfrag(const float* __restrict__ W1, bf16x8* __restrict__ Wfrag) {
    int ft = blockIdx.x * 256 + threadIdx.x;   // 8192 frag-lanes
    int c = ft >> 10, rem = ft & 1023;
    int nt = rem >> 6, l = rem & 63;
    int n = (l & 15) * 16 + nt;
    int k0 = c * 32 + (l >> 4) * 8;
    bf16x8 f;
    #pragma unroll
    for (int j = 0; j < 8; ++j)
        f[j] = (short)bf16_rn(W1[(k0 + j) * 256 + n]);
    Wfrag[ft] = f;
}

// ---------------- Layer 1 GEMM via bf16 MFMA + fused attention logits ----------------
// xp1b rows (640B): [0..511] bf16 channels, [512..543] as1[8] fp32, pad.
#define GM_GRID 782   // ceil(50000/64)
__global__ __launch_bounds__(128) void
k_gemm1m(const float* __restrict__ x, const bf16x8* __restrict__ Wfrag,
         unsigned short* __restrict__ xp1b,
         const float* __restrict__ asrc, const float* __restrict__ adst,
         float* __restrict__ ad1) {
    __shared__ bf16x8 lds[1024];   // one K=32 chunk of B frags: 16 KB
    int t = threadIdx.x, l = t & 63, w = t >> 6;
    int rowbase = blockIdx.x * 64 + w * 32;
    int m = l & 15, kg = l >> 4;

    f32x4 acc0[16], acc1[16];
    #pragma unroll
    for (int nt = 0; nt < 16; ++nt) {
        acc0[nt] = (f32x4){0.f, 0.f, 0.f, 0.f};
        acc1[nt] = (f32x4){0.f, 0.f, 0.f, 0.f};
    }

    int r0 = rowbase + m;
    int r1 = rowbase + 16 + m;
    if (r0 > N_NODES - 1) r0 = N_NODES - 1;   // clamp (results unused)
    if (r1 > N_NODES - 1) r1 = N_NODES - 1;
    const float4* x4 = (const float4*)x;

    for (int c = 0; c < 8; ++c) {
        __syncthreads();
        const bf16x8* src = Wfrag + c * 1024;
        #pragma unroll
        for (int q = 0; q < 8; ++q)
            lds[q * 128 + t] = src[q * 128 + t];
        __syncthreads();

        int kb = (c * 32 + kg * 8) >> 2;
        float4 xa0 = x4[r0 * 64 + kb], xb0 = x4[r0 * 64 + kb + 1];
        float4 xa1 = x4[r1 * 64 + kb], xb1 = x4[r1 * 64 + kb + 1];
        bf16x8 aF0, aF1;
        aF0[0] = (short)bf16_rn(xa0.x); aF0[1] = (short)bf16_rn(xa0.y);
        aF0[2] = (short)bf16_rn(xa0.z); aF0[3] = (short)bf16_rn(xa0.w);
        aF0[4] = (short)bf16_rn(xb0.x); aF0[5] = (short)bf16_rn(xb0.y);
        aF0[6] = (short)bf16_rn(xb0.z); aF0[7] = (short)bf16_rn(xb0.w);
        aF1[0] = (short)bf16_rn(xa1.x); aF1[1] = (short)bf16_rn(xa1.y);
        aF1[2] = (short)bf16_rn(xa1.z); aF1[3] = (short)bf16_rn(xa1.w);
        aF1[4] = (short)bf16_rn(xb1.x); aF1[5] = (short)bf16_rn(xb1.y);
        aF1[6] = (short)bf16_rn(xb1.z); aF1[7] = (short)bf16_rn(xb1.w);

        #pragma unroll
        for (int nt = 0; nt < 16; ++nt) {
            bf16x8 bF = lds[nt * 64 + l];
            acc0[nt] = __builtin_amdgcn_mfma_f32_16x16x32_bf16(aF0, bF, acc0[nt], 0, 0, 0);
            acc1[nt] = __builtin_amdgcn_mfma_f32_16x16x32_bf16(aF1, bF, acc1[nt], 0, 0, 0);
        }
    }

    // epilogue: lane holds channels cbase*16+nt of rows rq*4+reg (pi-permuted)
    int cbase = l & 15, rq = l >> 4;
    float asV[16], adV[16];
    #pragma unroll
    for (int q = 0; q < 4; ++q) {
        float4 sa = ((const float4*)asrc)[cbase * 4 + q];
        float4 da = ((const float4*)adst)[cbase * 4 + q];
        asV[q * 4 + 0] = sa.x; asV[q * 4 + 1] = sa.y; asV[q * 4 + 2] = sa.z; asV[q * 4 + 3] = sa.w;
        adV[q * 4 + 0] = da.x; adV[q * 4 + 1] = da.y; adV[q * 4 + 2] = da.z; adV[q * 4 + 3] = da.w;
    }
    #pragma unroll
    for (int g = 0; g < 2; ++g) {
        f32x4* A = g ? acc1 : acc0;
        #pragma unroll
        for (int reg = 0; reg < 4; ++reg) {
            int gr = rowbase + g * 16 + rq * 4 + reg;
            unsigned int ob[8];
            float ps = 0.f, pd = 0.f;
            #pragma unroll
            for (int q = 0; q < 8; ++q) {
                float v0 = A[2 * q][reg], v1 = A[2 * q + 1][reg];
                ob[q] = (unsigned int)bf16_rn(v0) | ((unsigned int)bf16_rn(v1) << 16);
                ps = fmaf(v0, asV[2 * q], ps);     ps = fmaf(v1, asV[2 * q + 1], ps);
                pd = fmaf(v0, adV[2 * q], pd);     pd = fmaf(v1, adV[2 * q + 1], pd);
            }
            ps += __shfl_xor(ps, 1);
            pd += __shfl_xor(pd, 1);
            if (gr < N_NODES) {
                unsigned short* row = xp1b + (size_t)gr * ROW_US;
                uint4* dst = (uint4*)(row + cbase * 16);
                dst[0] = make_uint4(ob[0], ob[1], ob[2], ob[3]);
                dst[1] = make_uint4(ob[4], ob[5], ob[6], ob[7]);
                if ((l & 1) == 0) {
                    ((float*)(row + 256))[cbase >> 1] = ps;   // as1 in-row
                    ad1[gr * 8 + (cbase >> 1)] = pd;
                }
            }
        }
    }
}

// ---------------- fused layer-1 softmax-aggregate + ReLU + layer-2 proj/logits ----
// Gather indices scalarized via readfirstlane (colb[j] is wave-uniform) ->
// SGPR row base + lane offset; as1 co-located in the row.
__global__ void k_agg1(const unsigned short* __restrict__ xp1b, const float* __restrict__ ad1,
                       const int* __restrict__ row_ptr, const int* __restrict__ colb,
                       const float* __restrict__ b1, const float* __restrict__ W2,
                       const float* __restrict__ as2w, const float* __restrict__ ad2w,
                       float* __restrict__ xp2, float* __restrict__ as2,
                       float* __restrict__ ad2) {
    int t = threadIdx.x, l = t & 63, w = t >> 6;
    int n = blockIdx.x * 4 + w;
    int hidx = l >> 3;
    float adn = ad1[n * 8 + hidx];
    int start = row_ptr[n], end = row_ptr[n + 1];
    const char* xb = (const char*)xp1b;
    int loff = 8 * l;
    int aoff = 512 + 4 * hidx;
    f32x2 accA = {0.f, 0.f}, accB = {0.f, 0.f};
    float den = 0.f;
    int j = start;
    for (; j + 8 <= end; j += 8) {
        int s0 = __builtin_amdgcn_readfirstlane(colb[j]);
        int s1 = __builtin_amdgcn_readfirstlane(colb[j + 1]);
        int s2 = __builtin_amdgcn_readfirstlane(colb[j + 2]);
        int s3 = __builtin_amdgcn_readfirstlane(colb[j + 3]);
        int s4 = __builtin_amdgcn_readfirstlane(colb[j + 4]);
        int s5 = __builtin_amdgcn_readfirstlane(colb[j + 5]);
        int s6 = __builtin_amdgcn_readfirstlane(colb[j + 6]);
        int s7 = __builtin_amdgcn_readfirstlane(colb[j + 7]);
        const char* p0 = xb + (size_t)s0 * 640;
        const char* p1 = xb + (size_t)s1 * 640;
        const char* p2 = xb + (size_t)s2 * 640;
        const char* p3 = xb + (size_t)s3 * 640;
        const char* p4 = xb + (size_t)s4 * 640;
        const char* p5 = xb + (size_t)s5 * 640;
        const char* p6 = xb + (size_t)s6 * 640;
        const char* p7 = xb + (size_t)s7 * 640;
        uint2 r0 = *(const uint2*)(p0 + loff);
        uint2 r1 = *(const uint2*)(p1 + loff);
        uint2 r2 = *(const uint2*)(p2 + loff);
        uint2 r3 = *(const uint2*)(p3 + loff);
        uint2 r4 = *(const uint2*)(p4 + loff);
        uint2 r5 = *(const uint2*)(p5 + loff);
        uint2 r6 = *(const uint2*)(p6 + loff);
        uint2 r7 = *(const uint2*)(p7 + loff);
        float e0 = *(const float*)(p0 + aoff) + adn;
        float e1 = *(const float*)(p1 + aoff) + adn;
        float e2 = *(const float*)(p2 + aoff) + adn;
        float e3 = *(const float*)(p3 + aoff) + adn;
        float e4 = *(const float*)(p4 + aoff) + adn;
        float e5 = *(const float*)(p5 + aoff) + adn;
        float e6 = *(const float*)(p6 + aoff) + adn;
        float e7 = *(const float*)(p7 + aoff) + adn;
        e0 = (e0 > 0.f) ? e0 : NEG * e0;
        e1 = (e1 > 0.f) ? e1 : NEG * e1;
        e2 = (e2 > 0.f) ? e2 : NEG * e2;
        e3 = (e3 > 0.f) ? e3 : NEG * e3;
        e4 = (e4 > 0.f) ? e4 : NEG * e4;
        e5 = (e5 > 0.f) ? e5 : NEG * e5;
        e6 = (e6 > 0.f) ? e6 : NEG * e6;
        e7 = (e7 > 0.f) ? e7 : NEG * e7;
        float p0e = __expf(e0), p1e = __expf(e1), p2e = __expf(e2), p3e = __expf(e3);
        float p4e = __expf(e4), p5e = __expf(e5), p6e = __expf(e6), p7e = __expf(e7);
        den += ((p0e + p1e) + (p2e + p3e)) + ((p4e + p5e) + (p6e + p7e));
        f32x2 q;
        q = (f32x2){p0e, p0e}; accA += q * bf2_unpack(r0.x); accB += q * bf2_unpack(r0.y);
        q = (f32x2){p1e, p1e}; accA += q * bf2_unpack(r1.x); accB += q * bf2_unpack(r1.y);
        q = (f32x2){p2e, p2e}; accA += q * bf2_unpack(r2.x); accB += q * bf2_unpack(r2.y);
        q = (f32x2){p3e, p3e}; accA += q * bf2_unpack(r3.x); accB += q * bf2_unpack(r3.y);
        q = (f32x2){p4e, p4e}; accA += q * bf2_unpack(r4.x); accB += q * bf2_unpack(r4.y);
        q = (f32x2){p5e, p5e}; accA += q * bf2_unpack(r5.x); accB += q * bf2_unpack(r5.y);
        q = (f32x2){p6e, p6e}; accA += q * bf2_unpack(r6.x); accB += q * bf2_unpack(r6.y);
        q = (f32x2){p7e, p7e}; accA += q * bf2_unpack(r7.x); accB += q * bf2_unpack(r7.y);
    }
    for (; j < end; ++j) {
        int s = __builtin_amdgcn_readfirstlane(colb[j]);
        const char* p = xb + (size_t)s * 640;
        uint2 r = *(const uint2*)(p + loff);
        float e = *(const float*)(p + aoff) + adn;
        e = (e > 0.f) ? e : NEG * e;
        float pe = __expf(e);
        den += pe;
        f32x2 q = {pe, pe};
        accA += q * bf2_unpack(r.x);
        accB += q * bf2_unpack(r.y);
    }
    float4 bv = ((const float4*)b1)[l];
    float inv = 1.f / den;
    float4 o;
    o.x = fmaxf(accA[0] * inv + bv.x, 0.f);
    o.y = fmaxf(accA[1] * inv + bv.y, 0.f);
    o.z = fmaxf(accB[0] * inv + bv.z, 0.f);
    o.w = fmaxf(accB[1] * inv + bv.w, 0.f);
    // fused proj2: W2 row-major (256,2); lane l holds channels 4l..4l+3
    float4 wa = ((const float4*)W2)[2 * l];
    float4 wb = ((const float4*)W2)[2 * l + 1];
    float d0 = o.x * wa.x + o.y * wa.z + o.z * wb.x + o.w * wb.z;
    float d1 = o.x * wa.y + o.y * wa.w + o.z * wb.y + o.w * wb.w;
    #pragma unroll
    for (int m = 1; m < 64; m <<= 1) {
        d0 += __shfl_xor(d0, m);
        d1 += __shfl_xor(d1, m);
    }
    if (l == 0) {
        xp2[2 * n] = d0;
        xp2[2 * n + 1] = d1;
        as2[n] = d0 * as2w[0] + d1 * as2w[1];
        ad2[n] = d0 * ad2w[0] + d1 * ad2w[1];
    }
}

// ---------------- segment-softmax + aggregate, layer 2: node-per-lane ----------------
__global__ void k_agg2(const float* __restrict__ xp2, const float* __restrict__ as2,
                       const float* __restrict__ ad2, const int* __restrict__ row_ptr,
                       const int* __restrict__ colb, const float* __restrict__ b2,
                       float* __restrict__ out) {
    int n = blockIdx.x * 256 + threadIdx.x;
    if (n >= N_NODES) return;
    int start = row_ptr[n], end = row_ptr[n + 1];
    float adn = ad2[n];
    float b20 = b2[0], b21 = b2[1];
    float a0 = 0.f, a1 = 0.f, den = 0.f;
    const float2* xpv = (const float2*)xp2;
    for (int j = start; j < end; ++j) {
        int s = colb[j];
        float e = as2[s] + adn;
        e = (e > 0.f) ? e : NEG * e;
        float p = __expf(e);
        den += p;
        float2 v = xpv[s];
        a0 = fmaf(p, v.x, a0);
        a1 = fmaf(p, v.y, a1);
    }
    float inv = 1.f / den;
    ((float2*)out)[n] = make_float2(a0 * inv + b20, a1 * inv + b21);
}

extern "C" void kernel_launch(void* const* d_in, const int* in_sizes, int n_in,
                              void* d_out, int out_size, void* d_ws, size_t ws_size,
                              hipStream_t stream) {
    const float* x     = (const float*)d_in[0];
    const int*   ei    = (const int*)d_in[1];
    const float* W1    = (const float*)d_in[2];
    const float* asrc1 = (const float*)d_in[3];
    const float* adst1 = (const float*)d_in[4];
    const float* b1    = (const float*)d_in[5];
    const float* W2    = (const float*)d_in[6];
    const float* asrc2 = (const float*)d_in[7];
    const float* adst2 = (const float*)d_in[8];
    const float* b2    = (const float*)d_in[9];
    float* out = (float*)d_out;

    char* ws = (char*)d_ws;
    unsigned short* xp1b = (unsigned short*)(ws + 0);   // 32,000,000 B (640B rows)
    bf16x8* Wfrag  = (bf16x8*)(ws + 32000000);      //    131,072 B
    float* ad1     = (float*)(ws + 32200000);       //  1,600,000 B
    float* xp2     = (float*)(ws + 33800000);       //    400,000 B
    float* as2     = (float*)(ws + 34200000);       //    200,000 B
    float* ad2     = (float*)(ws + 34400000);       //    200,000 B
    int*   counts  = (int*)  (ws + 34600000);       //    200,000 B
    int*   fill    = (int*)  (ws + 34800000);       //    200,000 B (contig w/ counts)
    int*   row_ptr = (int*)  (ws + 35000000);       //    200,064 B
    int*   colb    = (int*)  (ws + 35200064);       //  3,400,000 B
    int*   bsums   = (int*)  (ws + 38600064);       //        256 B

    hipMemsetAsync(counts, 0, 400000, stream);      // counts + fill

    int egrid = (EP + 255) / 256;
    k_hist      <<<egrid,       256, 0, stream>>>(ei, counts);
    k_scan_block<<<SCAN_BLOCKS, 256, 0, stream>>>(counts, row_ptr, bsums);
    k_scan_add  <<<SCAN_BLOCKS, 256, 0, stream>>>(row_ptr, bsums);
    k_scatter   <<<egrid,       256, 0, stream>>>(ei, row_ptr, fill, colb);
    k_cvtWfrag  <<<32,     256, 0, stream>>>(W1, Wfrag);

    k_gemm1m <<<GM_GRID, 128, 0, stream>>>(x, Wfrag, xp1b, asrc1, adst1, ad1);
    k_agg1   <<<12500,  256, 0, stream>>>(xp1b, ad1, row_ptr, colb,
                                          b1, W2, asrc2, adst2, xp2, as2, ad2);
    k_agg2   <<<196,    256, 0, stream>>>(xp2, as2, ad2, row_ptr, colb, b2, out);
}